// Round 1
// baseline (2137.020 us; speedup 1.0000x reference)
//
#include <hip/hip_runtime.h>

// Problem shape: X [N,128] fp32, y [N] int32, C classes (scalar on device).
// out [N, 384] = [X | global_mean | class_mean[y]].
static constexpr int D  = 128;  // feature dim (fixed by problem)
static constexpr int D4 = 32;   // float4s per row of X

// Workspace layout (computed on device since C lives in device memory):
//   sums   : C*D floats   (class sums, atomically accumulated)
//   counts : C ints       (class counts)
//   gmean  : D floats
//   cmean  : C*D floats
struct Ptrs {
  float* sums;
  int*   counts;
  float* gmean;
  float* cmean;
};

__device__ __forceinline__ Ptrs get_ptrs(void* ws, int C) {
  Ptrs p;
  p.sums   = reinterpret_cast<float*>(ws);                 // C*D*4 bytes, D=128 -> 16B aligned
  p.counts = reinterpret_cast<int*>(p.sums + (size_t)C * D);
  const int Cpad = (C + 3) & ~3;                           // keep following ptrs 16B aligned
  p.gmean  = reinterpret_cast<float*>(p.counts + Cpad);
  p.cmean  = p.gmean + D;
  return p;
}

// Zero sums + counts (word-zero works for both fp32 and int).
__global__ void zero_ws_kernel(void* ws, const int* __restrict__ ncp) {
  const int C = *ncp;
  const int total = C * D + ((C + 3) & ~3);
  int* w = reinterpret_cast<int*>(ws);
  for (int i = blockIdx.x * blockDim.x + threadIdx.x; i < total;
       i += gridDim.x * blockDim.x)
    w[i] = 0;
}

// Pass 1: stream X once. Copy X into out[:, 0:128] and atomically accumulate
// per-class sums/counts. 256 threads = 8 groups of 32 lanes; one row per
// group per iteration; float4 (16B) per lane -> fully coalesced 512B rows.
__global__ void accum_kernel(const float* __restrict__ X, const int* __restrict__ y,
                             const int* __restrict__ ncp, float* __restrict__ out,
                             void* ws, int n) {
  const int C = *ncp;
  Ptrs p = get_ptrs(ws, C);
  const int g    = threadIdx.x >> 5;   // row-group 0..7
  const int lane = threadIdx.x & 31;   // float4 slot within row
  const long long stride = (long long)gridDim.x * 8;
  for (long long row = (long long)blockIdx.x * 8 + g; row < n; row += stride) {
    int c = y[row];
    c = min(max(c, 0), C - 1);
    const float4 v = reinterpret_cast<const float4*>(X)[row * D4 + lane];
    reinterpret_cast<float4*>(out)[row * (3 * D4) + lane] = v;  // out[:,0:128]
    float* s = p.sums + (size_t)c * D + lane * 4;
    unsafeAtomicAdd(s + 0, v.x);   // hardware global_atomic_add_f32
    unsafeAtomicAdd(s + 1, v.y);
    unsafeAtomicAdd(s + 2, v.z);
    unsafeAtomicAdd(s + 3, v.w);
    if (lane == 0) atomicAdd(p.counts + c, 1);
  }
}

// Pass 2a: global mean = (sum over classes of class sums) / N.
// One block of 1024 threads = 8 groups x 128 dims; LDS tree-reduce.
__global__ void gmean_kernel(void* ws, const int* __restrict__ ncp, float invN) {
  const int C = *ncp;
  Ptrs p = get_ptrs(ws, C);
  __shared__ float red[8][D];
  const int d = threadIdx.x & (D - 1);
  const int g = threadIdx.x >> 7;  // 0..7
  float acc = 0.f;
  for (int c = g; c < C; c += 8) acc += p.sums[c * D + d];
  red[g][d] = acc;
  __syncthreads();
  if (g == 0) {
    float t = 0.f;
#pragma unroll
    for (int k = 0; k < 8; ++k) t += red[k][d];
    p.gmean[d] = t * invN;
  }
}

// Pass 2b: class means with empty-class fallback to global mean.
__global__ void cmean_kernel(void* ws, const int* __restrict__ ncp) {
  const int C = *ncp;
  Ptrs p = get_ptrs(ws, C);
  const int total = C * D;
  for (int i = blockIdx.x * blockDim.x + threadIdx.x; i < total;
       i += gridDim.x * blockDim.x) {
    const int cnt = p.counts[i >> 7];
    p.cmean[i] = (cnt > 0) ? (p.sums[i] / (float)cnt) : p.gmean[i & (D - 1)];
  }
}

// Pass 3: write out[:, 128:384). 64 float4 per row: q<32 -> global mean,
// q>=32 -> class mean row (512B coalesced read, L2-resident).
__global__ void write_kernel(const int* __restrict__ y, const int* __restrict__ ncp,
                             float* __restrict__ out, void* ws, int n) {
  const int C = *ncp;
  Ptrs p = get_ptrs(ws, C);
  const float4* gm4  = reinterpret_cast<const float4*>(p.gmean);
  const float4* cm4  = reinterpret_cast<const float4*>(p.cmean);
  float4*       out4 = reinterpret_cast<float4*>(out);
  const long long total  = (long long)n * 64;
  const long long stride = (long long)gridDim.x * blockDim.x;
  for (long long idx = (long long)blockIdx.x * blockDim.x + threadIdx.x;
       idx < total; idx += stride) {
    const long long row = idx >> 6;
    const int q = (int)(idx & 63);
    float4 v;
    if (q < D4) {
      v = gm4[q];
    } else {
      int c = y[row];
      c = min(max(c, 0), C - 1);
      v = cm4[(size_t)c * D4 + (q - D4)];
    }
    out4[row * (3 * D4) + D4 + q] = v;
  }
}

extern "C" void kernel_launch(void* const* d_in, const int* in_sizes, int n_in,
                              void* d_out, int out_size, void* d_ws, size_t ws_size,
                              hipStream_t stream) {
  const float* X   = reinterpret_cast<const float*>(d_in[0]);
  const int*   y   = reinterpret_cast<const int*>(d_in[1]);
  const int*   ncp = reinterpret_cast<const int*>(d_in[2]);
  float*       out = reinterpret_cast<float*>(d_out);
  const int n = in_sizes[1];                 // N = 1e6 (len(y))
  const float invN = 1.0f / (float)n;

  zero_ws_kernel<<<256, 256, 0, stream>>>(d_ws, ncp);
  accum_kernel<<<4096, 256, 0, stream>>>(X, y, ncp, out, d_ws, n);
  gmean_kernel<<<1, 1024, 0, stream>>>(d_ws, ncp, invN);
  cmean_kernel<<<512, 256, 0, stream>>>(d_ws, ncp);
  write_kernel<<<8192, 256, 0, stream>>>(y, ncp, out, d_ws, n);
}

// Round 2
// 947.506 us; speedup vs baseline: 2.2554x; 2.2554x over previous
//
#include <hip/hip_runtime.h>

// out [N, 384] = [X | global_mean | class_mean[y]].  X [N,128] fp32, y [N] i32.
static constexpr int D      = 128;          // feature dim
static constexpr int D4     = 32;           // float4s per X row
static constexpr int CMAX   = 1024;         // layout capacity for classes (C=1000)
static constexpr int GSLICE = 16;           // dims per dim-group
static constexpr int NG     = D / GSLICE;   // 8 dim-groups
static constexpr int SLICE4 = GSLICE / 4;   // 4 float4 lanes per slice

// Fixed workspace region (CMAX-based so host & device agree without reading C):
//   sums[CMAX*D] f32 | counts[CMAX] i32 | gmean[D] f32 | cmean[CMAX*D] f32
struct Ptrs {
  float* sums;
  int*   counts;
  float* gmean;
  float* cmean;
};
__device__ __forceinline__ Ptrs get_ptrs(void* ws) {
  Ptrs p;
  p.sums   = reinterpret_cast<float*>(ws);
  p.counts = reinterpret_cast<int*>(p.sums + (size_t)CMAX * D);
  p.gmean  = reinterpret_cast<float*>(p.counts + CMAX);
  p.cmean  = p.gmean + D;
  return p;
}
static constexpr size_t FIXED_BYTES =
    ((size_t)CMAX * D + CMAX + D + (size_t)CMAX * D) * 4;
static constexpr size_t PER_CHUNK_BYTES = (size_t)NG * CMAX * GSLICE * 4;  // 512 KB

// ---------------- LDS-privatized path ----------------

// Zero the global counts (accumulated by int atomics in accum_lds_kernel).
__global__ void zero_counts_kernel(void* ws) {
  Ptrs p = get_ptrs(ws);
  for (int i = threadIdx.x; i < CMAX; i += blockDim.x) p.counts[i] = 0;
}

// One block = (dim-group g, row-chunk). Streams its rows' 64B column slice of
// X: copies it into out[:,0:128] and ds_add-accumulates per-class sums in LDS.
// Dumps the 64KB LDS partial non-atomically to psums[bid].
__global__ __launch_bounds__(512) void accum_lds_kernel(
    const float* __restrict__ X, const int* __restrict__ y,
    const int* __restrict__ ncp, float* __restrict__ out, void* ws,
    float* __restrict__ psums, int n, int rpc) {
  __shared__ float smem[CMAX * GSLICE];  // 64 KB
  const int C = *ncp;
  Ptrs p = get_ptrs(ws);
  const int g     = blockIdx.x % NG;
  const int chunk = blockIdx.x / NG;
  for (int i = threadIdx.x; i < CMAX * GSLICE; i += blockDim.x) smem[i] = 0.f;
  __syncthreads();

  const int lane = threadIdx.x & (SLICE4 - 1);  // float4 slot in slice (0..3)
  const int rl   = threadIdx.x >> 2;            // local row (0..127)
  const int rows_per_iter = blockDim.x >> 2;    // 128
  long long r0 = (long long)chunk * rpc;
  long long r1 = r0 + rpc;
  if (r1 > n) r1 = n;
  for (long long row = r0 + rl; row < r1; row += rows_per_iter) {
    int c = y[row];
    c = min(max(c, 0), C - 1);
    const float4 v =
        reinterpret_cast<const float4*>(X)[row * D4 + g * SLICE4 + lane];
    reinterpret_cast<float4*>(out)[row * (3 * D4) + g * SLICE4 + lane] = v;
    float* s = smem + c * GSLICE + lane * 4;
    atomicAdd(s + 0, v.x);  // ds_add_f32 (LDS-scope, no HBM traffic)
    atomicAdd(s + 1, v.y);
    atomicAdd(s + 2, v.z);
    atomicAdd(s + 3, v.w);
    if (g == 0 && lane == 0) atomicAdd(p.counts + c, 1);  // 1M int atomics total
  }
  __syncthreads();
  // Non-atomic 64KB contiguous dump of this block's partial.
  float4*       dst = reinterpret_cast<float4*>(psums) +
                      (size_t)blockIdx.x * (CMAX * GSLICE / 4);
  const float4* src = reinterpret_cast<const float4*>(smem);
  for (int i = threadIdx.x; i < CMAX * GSLICE / 4; i += blockDim.x) dst[i] = src[i];
}

// sums[c][dg] = sum over chunks of psums[chunk*NG+g][c][dl].
__global__ void reduce_kernel(void* ws, const float* __restrict__ psums,
                              const int* __restrict__ ncp, int nchunk) {
  const int C = *ncp;
  Ptrs p = get_ptrs(ws);
  const int total = C * D;
  for (int e = blockIdx.x * blockDim.x + threadIdx.x; e < total;
       e += gridDim.x * blockDim.x) {
    const int c  = e >> 7;
    const int dg = e & (D - 1);
    const int g  = dg >> 4;
    const int dl = dg & (GSLICE - 1);
    float acc = 0.f;
    for (int k = 0; k < nchunk; ++k)
      acc += psums[((size_t)(k * NG + g) * CMAX + c) * GSLICE + dl];
    p.sums[e] = acc;
  }
}

// ---------------- fallback path (global atomics; proven r0) ----------------

__global__ void zero_ws_kernel(void* ws) {
  int* w = reinterpret_cast<int*>(ws);
  const int total = CMAX * D + CMAX;  // sums + counts
  for (int i = blockIdx.x * blockDim.x + threadIdx.x; i < total;
       i += gridDim.x * blockDim.x)
    w[i] = 0;
}

__global__ void accum_atomic_kernel(const float* __restrict__ X,
                                    const int* __restrict__ y,
                                    const int* __restrict__ ncp,
                                    float* __restrict__ out, void* ws, int n) {
  const int C = *ncp;
  Ptrs p = get_ptrs(ws);
  const int g    = threadIdx.x >> 5;
  const int lane = threadIdx.x & 31;
  const long long stride = (long long)gridDim.x * 8;
  for (long long row = (long long)blockIdx.x * 8 + g; row < n; row += stride) {
    int c = y[row];
    c = min(max(c, 0), C - 1);
    const float4 v = reinterpret_cast<const float4*>(X)[row * D4 + lane];
    reinterpret_cast<float4*>(out)[row * (3 * D4) + lane] = v;
    float* s = p.sums + (size_t)c * D + lane * 4;
    unsafeAtomicAdd(s + 0, v.x);
    unsafeAtomicAdd(s + 1, v.y);
    unsafeAtomicAdd(s + 2, v.z);
    unsafeAtomicAdd(s + 3, v.w);
    if (lane == 0) atomicAdd(p.counts + c, 1);
  }
}

// ---------------- means + writer ----------------

__global__ void gmean_kernel(void* ws, const int* __restrict__ ncp, float invN) {
  const int C = *ncp;
  Ptrs p = get_ptrs(ws);
  __shared__ float red[8][D];
  const int d = threadIdx.x & (D - 1);
  const int g = threadIdx.x >> 7;
  float acc = 0.f;
  for (int c = g; c < C; c += 8) acc += p.sums[c * D + d];
  red[g][d] = acc;
  __syncthreads();
  if (g == 0) {
    float t = 0.f;
#pragma unroll
    for (int k = 0; k < 8; ++k) t += red[k][d];
    p.gmean[d] = t * invN;
  }
}

__global__ void cmean_kernel(void* ws, const int* __restrict__ ncp) {
  const int C = *ncp;
  Ptrs p = get_ptrs(ws);
  const int total = C * D;
  for (int i = blockIdx.x * blockDim.x + threadIdx.x; i < total;
       i += gridDim.x * blockDim.x) {
    const int cnt = p.counts[i >> 7];
    p.cmean[i] = (cnt > 0) ? (p.sums[i] / (float)cnt) : p.gmean[i & (D - 1)];
  }
}

// out[:, 128:384): q<32 -> global mean, q>=32 -> class-mean row (L2-resident).
__global__ void write_kernel(const int* __restrict__ y,
                             const int* __restrict__ ncp,
                             float* __restrict__ out, void* ws, int n) {
  const int C = *ncp;
  Ptrs p = get_ptrs(ws);
  const float4* gm4  = reinterpret_cast<const float4*>(p.gmean);
  const float4* cm4  = reinterpret_cast<const float4*>(p.cmean);
  float4*       out4 = reinterpret_cast<float4*>(out);
  const long long total  = (long long)n * 64;
  const long long stride = (long long)gridDim.x * blockDim.x;
  for (long long idx = (long long)blockIdx.x * blockDim.x + threadIdx.x;
       idx < total; idx += stride) {
    const long long row = idx >> 6;
    const int q = (int)(idx & 63);
    float4 v;
    if (q < D4) {
      v = gm4[q];
    } else {
      int c = y[row];
      c = min(max(c, 0), C - 1);
      v = cm4[(size_t)c * D4 + (q - D4)];
    }
    out4[row * (3 * D4) + D4 + q] = v;
  }
}

extern "C" void kernel_launch(void* const* d_in, const int* in_sizes, int n_in,
                              void* d_out, int out_size, void* d_ws,
                              size_t ws_size, hipStream_t stream) {
  const float* X   = reinterpret_cast<const float*>(d_in[0]);
  const int*   y   = reinterpret_cast<const int*>(d_in[1]);
  const int*   ncp = reinterpret_cast<const int*>(d_in[2]);
  float*       out = reinterpret_cast<float*>(d_out);
  const int n = in_sizes[1];  // N = len(y)
  const float invN = 1.0f / (float)n;

  int nchunk = 0;
  if (ws_size > FIXED_BYTES)
    nchunk = (int)((ws_size - FIXED_BYTES) / PER_CHUNK_BYTES);
  if (nchunk > 64) nchunk = 64;  // 8*64 = 512 blocks = 2/CU (LDS-limited)

  if (nchunk >= 8) {
    const int rpc = (n + nchunk - 1) / nchunk;
    float* psums = reinterpret_cast<float*>((char*)d_ws + FIXED_BYTES);
    zero_counts_kernel<<<1, 256, 0, stream>>>(d_ws);
    accum_lds_kernel<<<NG * nchunk, 512, 0, stream>>>(X, y, ncp, out, d_ws,
                                                      psums, n, rpc);
    reduce_kernel<<<512, 256, 0, stream>>>(d_ws, psums, ncp, nchunk);
  } else {
    // ws too small for partials: proven global-atomic path (slow but correct).
    zero_ws_kernel<<<256, 256, 0, stream>>>(d_ws);
    accum_atomic_kernel<<<4096, 256, 0, stream>>>(X, y, ncp, out, d_ws, n);
  }
  gmean_kernel<<<1, 1024, 0, stream>>>(d_ws, ncp, invN);
  cmean_kernel<<<512, 256, 0, stream>>>(d_ws, ncp);
  write_kernel<<<8192, 256, 0, stream>>>(y, ncp, out, d_ws, n);
}

// Round 3
// 707.969 us; speedup vs baseline: 3.0185x; 1.3383x over previous
//
#include <hip/hip_runtime.h>

// out [N, 384] = [X | global_mean | class_mean[y]].  X [N,128] fp32, y [N] i32.
static constexpr int D    = 128;   // feature dim
static constexpr int D2   = 64;    // float2s per row
static constexpr int D4   = 32;    // float4s per row
static constexpr int CMAX = 1024;  // capacity for classes (C=1000)

typedef float f32x2 __attribute__((ext_vector_type(2)));
typedef float f32x4 __attribute__((ext_vector_type(4)));

// Fixed-offset workspace (CMAX-based so host & device agree without reading C):
//   sums[CMAX*D] f32 | counts[CMAX] i32 | base[CMAX] i32 | cursor[CMAX] i32 |
//   gmean[D] f32 | cmean[CMAX*D] f32 | rowid[N] i32
struct Ptrs {
  float* sums;
  int*   counts;
  int*   base;
  int*   cursor;
  float* gmean;
  float* cmean;
};
__device__ __forceinline__ Ptrs get_ptrs(void* ws) {
  Ptrs p;
  p.sums   = reinterpret_cast<float*>(ws);
  p.counts = reinterpret_cast<int*>(p.sums + (size_t)CMAX * D);
  p.base   = p.counts + CMAX;
  p.cursor = p.base + CMAX;
  p.gmean  = reinterpret_cast<float*>(p.cursor + CMAX);
  p.cmean  = p.gmean + D;
  return p;
}
static constexpr size_t FIXED_BYTES =
    ((size_t)CMAX * D + 3 * (size_t)CMAX + D + (size_t)CMAX * D) * 4;

__device__ __forceinline__ int clampc(int c, int C) {
  return min(max(c, 0), C - 1);
}

// ---------- sort pipeline ----------

__global__ void zero_counts_kernel(void* ws) {
  get_ptrs(ws).counts[threadIdx.x] = 0;  // <<<1, CMAX>>>
}

// S1: per-block LDS histogram of y, merged with global int atomics.
__global__ void count_kernel(const int* __restrict__ y,
                             const int* __restrict__ ncp, void* ws, int n) {
  __shared__ int lh[CMAX];
  const int C = min(*ncp, CMAX);
  Ptrs p = get_ptrs(ws);
  for (int i = threadIdx.x; i < CMAX; i += blockDim.x) lh[i] = 0;
  __syncthreads();
  for (int i = blockIdx.x * blockDim.x + threadIdx.x; i < n;
       i += gridDim.x * blockDim.x)
    atomicAdd(&lh[clampc(y[i], C)], 1);
  __syncthreads();
  for (int c = threadIdx.x; c < CMAX; c += blockDim.x)
    if (lh[c]) atomicAdd(&p.counts[c], lh[c]);
}

// S2: exclusive scan of counts -> base (segment starts) + cursor (working).
__global__ void scan_kernel(void* ws) {  // <<<1, CMAX>>>
  Ptrs p = get_ptrs(ws);
  __shared__ int s[CMAX];
  const int t  = threadIdx.x;
  const int my = p.counts[t];
  s[t] = my;
  __syncthreads();
  for (int off = 1; off < CMAX; off <<= 1) {
    const int add = (t >= off) ? s[t - off] : 0;
    __syncthreads();
    s[t] += add;
    __syncthreads();
  }
  const int excl = s[t] - my;
  p.base[t]   = excl;
  p.cursor[t] = excl;
}

// S3: scatter row ids into class-sorted order. Per block: LDS count of its
// contiguous row range, one batched global reservation per present class,
// then local placement (no per-row global atomics).
__global__ void scatter_kernel(const int* __restrict__ y,
                               const int* __restrict__ ncp, void* ws,
                               int* __restrict__ rowid, int n, int rpb) {
  __shared__ int lcnt[CMAX];
  __shared__ int lbase[CMAX];
  const int C = min(*ncp, CMAX);
  Ptrs p = get_ptrs(ws);
  for (int i = threadIdx.x; i < CMAX; i += blockDim.x) lcnt[i] = 0;
  __syncthreads();
  const int r0 = blockIdx.x * rpb;
  const int r1 = min(r0 + rpb, n);
  for (int i = r0 + threadIdx.x; i < r1; i += blockDim.x)
    atomicAdd(&lcnt[clampc(y[i], C)], 1);
  __syncthreads();
  for (int c = threadIdx.x; c < CMAX; c += blockDim.x) {
    const int k = lcnt[c];
    lbase[c] = k ? atomicAdd(&p.cursor[c], k) : 0;
    lcnt[c]  = 0;
  }
  __syncthreads();
  for (int i = r0 + threadIdx.x; i < r1; i += blockDim.x) {
    const int c   = clampc(y[i], C);
    const int pos = lbase[c] + atomicAdd(&lcnt[c], 1);
    rowid[pos] = i;
  }
}

// S4: one block per class; gather full 512B rows (one wave = one row as
// float2/lane), accumulate in registers, LDS tree-reduce across 8 waves.
__global__ __launch_bounds__(512) void gather_kernel(
    const float* __restrict__ X, const int* __restrict__ ncp, void* ws,
    const int* __restrict__ rowid) {
  const int C = min(*ncp, CMAX);
  Ptrs p = get_ptrs(ws);
  const int c   = blockIdx.x;
  const int cnt = (c < C) ? p.counts[c] : 0;
  const int b   = p.base[c];
  const int d2  = threadIdx.x & (D2 - 1);  // float2 slot in row
  const int sub = threadIdx.x >> 6;        // wave id 0..7
  const f32x2* X2 = reinterpret_cast<const f32x2*>(X);
  f32x2 acc = {0.f, 0.f};
  int i = sub;
  for (; i + 8 < cnt; i += 16) {  // 2 rows in flight per wave
    const int ra = rowid[b + i];
    const int rb = rowid[b + i + 8];
    const f32x2 va = __builtin_nontemporal_load(&X2[(size_t)ra * D2 + d2]);
    const f32x2 vb = __builtin_nontemporal_load(&X2[(size_t)rb * D2 + d2]);
    acc += va;
    acc += vb;
  }
  for (; i < cnt; i += 8)
    acc += __builtin_nontemporal_load(&X2[(size_t)rowid[b + i] * D2 + d2]);
  __shared__ f32x2 red[8][D2];
  red[sub][d2] = acc;
  __syncthreads();
  if (sub == 0) {
    f32x2 t = acc;
#pragma unroll
    for (int k = 1; k < 8; ++k) t += red[k][d2];
    reinterpret_cast<f32x2*>(p.sums)[(size_t)c * D2 + d2] = t;
  }
}

// ---------- fallback accumulate (ws too small): global fp32 atomics ----------

__global__ void zero_sums_counts_kernel(void* ws) {
  int* w = reinterpret_cast<int*>(ws);
  const int total = CMAX * D + CMAX;
  for (int i = blockIdx.x * blockDim.x + threadIdx.x; i < total;
       i += gridDim.x * blockDim.x)
    w[i] = 0;
}

__global__ void accum_atomic_kernel(const float* __restrict__ X,
                                    const int* __restrict__ y,
                                    const int* __restrict__ ncp, void* ws,
                                    int n) {
  const int C = min(*ncp, CMAX);
  Ptrs p = get_ptrs(ws);
  const int g    = threadIdx.x >> 5;
  const int lane = threadIdx.x & 31;
  const long long stride = (long long)gridDim.x * 8;
  for (long long row = (long long)blockIdx.x * 8 + g; row < n; row += stride) {
    const int c = clampc(y[row], C);
    const float4 v = reinterpret_cast<const float4*>(X)[row * D4 + lane];
    float* s = p.sums + (size_t)c * D + lane * 4;
    unsafeAtomicAdd(s + 0, v.x);
    unsafeAtomicAdd(s + 1, v.y);
    unsafeAtomicAdd(s + 2, v.z);
    unsafeAtomicAdd(s + 3, v.w);
    if (lane == 0) atomicAdd(p.counts + c, 1);
  }
}

// ---------- means ----------

__global__ void gmean_kernel(void* ws, const int* __restrict__ ncp, float invN) {
  const int C = min(*ncp, CMAX);
  Ptrs p = get_ptrs(ws);
  __shared__ float red[8][D];
  const int d = threadIdx.x & (D - 1);
  const int g = threadIdx.x >> 7;
  float acc = 0.f;
  for (int c = g; c < C; c += 8) acc += p.sums[c * D + d];
  red[g][d] = acc;
  __syncthreads();
  if (g == 0) {
    float t = 0.f;
#pragma unroll
    for (int k = 0; k < 8; ++k) t += red[k][d];
    p.gmean[d] = t * invN;
  }
}

__global__ void cmean_kernel(void* ws, const int* __restrict__ ncp) {
  const int C = min(*ncp, CMAX);
  Ptrs p = get_ptrs(ws);
  const int total = C * D;
  for (int i = blockIdx.x * blockDim.x + threadIdx.x; i < total;
       i += gridDim.x * blockDim.x) {
    const int cnt = p.counts[i >> 7];
    p.cmean[i] = (cnt > 0) ? (p.sums[i] / (float)cnt) : p.gmean[i & (D - 1)];
  }
}

// ---------- monolithic sequential writer ----------
// Block = 384 threads = 4 whole rows (96 float4 each). Writes full 1536B rows
// sequentially with NT stores; reads X sequentially; gmean hoisted to regs;
// cmean gathers stay L2-hot (NT stores keep them uncached-polluted).
__global__ __launch_bounds__(384) void write_kernel(
    const float* __restrict__ X, const int* __restrict__ y,
    const int* __restrict__ ncp, float* __restrict__ out, void* ws, int n) {
  const int C = min(*ncp, CMAX);
  Ptrs p = get_ptrs(ws);
  const f32x4* X4  = reinterpret_cast<const f32x4*>(X);
  const f32x4* gm4 = reinterpret_cast<const f32x4*>(p.gmean);
  const f32x4* cm4 = reinterpret_cast<const f32x4*>(p.cmean);
  f32x4*       o4  = reinterpret_cast<f32x4*>(out);
  const int j  = threadIdx.x % 96;
  const int lr = threadIdx.x / 96;
  f32x4 vg;
  if (j >= D4 && j < 2 * D4) vg = gm4[j - D4];  // loop-invariant gmean slice
  const long long rpi = (long long)gridDim.x * 4;
  for (long long row = (long long)blockIdx.x * 4 + lr; row < n; row += rpi) {
    f32x4 v;
    if (j < D4) {
      v = __builtin_nontemporal_load(&X4[(size_t)row * D4 + j]);
    } else if (j < 2 * D4) {
      v = vg;
    } else {
      const int c = clampc(y[row], C);
      v = cm4[(size_t)c * D4 + (j - 2 * D4)];
    }
    __builtin_nontemporal_store(v, &o4[(size_t)row * 96 + j]);
  }
}

extern "C" void kernel_launch(void* const* d_in, const int* in_sizes, int n_in,
                              void* d_out, int out_size, void* d_ws,
                              size_t ws_size, hipStream_t stream) {
  const float* X   = reinterpret_cast<const float*>(d_in[0]);
  const int*   y   = reinterpret_cast<const int*>(d_in[1]);
  const int*   ncp = reinterpret_cast<const int*>(d_in[2]);
  float*       out = reinterpret_cast<float*>(d_out);
  const int n = in_sizes[1];  // N = len(y)
  const float invN = 1.0f / (float)n;

  const size_t need = FIXED_BYTES + (size_t)n * sizeof(int);
  if (ws_size >= need) {
    int* rowid = reinterpret_cast<int*>((char*)d_ws + FIXED_BYTES);
    const int rpb = (n + 255) / 256;
    zero_counts_kernel<<<1, CMAX, 0, stream>>>(d_ws);
    count_kernel<<<256, 256, 0, stream>>>(y, ncp, d_ws, n);
    scan_kernel<<<1, CMAX, 0, stream>>>(d_ws);
    scatter_kernel<<<256, 256, 0, stream>>>(y, ncp, d_ws, rowid, n, rpb);
    gather_kernel<<<CMAX, 512, 0, stream>>>(X, ncp, d_ws, rowid);
  } else {
    zero_sums_counts_kernel<<<256, 256, 0, stream>>>(d_ws);
    accum_atomic_kernel<<<4096, 256, 0, stream>>>(X, y, ncp, d_ws, n);
  }
  gmean_kernel<<<1, 1024, 0, stream>>>(d_ws, ncp, invN);
  cmean_kernel<<<512, 256, 0, stream>>>(d_ws, ncp);
  write_kernel<<<2048, 384, 0, stream>>>(X, y, ncp, out, d_ws, n);
}

// Round 4
// 498.468 us; speedup vs baseline: 4.2872x; 1.4203x over previous
//
#include <hip/hip_runtime.h>

// out [N, 384] = [X | global_mean | class_mean[y]].  X [N,128] fp32, y [N] i32.
static constexpr int D    = 128;   // feature dim
static constexpr int D2   = 64;    // float2s per row
static constexpr int D4   = 32;    // float4s per row
static constexpr int CMAX = 1024;  // capacity for classes (C=1000)
static constexpr int RCAP = 4096;  // rowids staged in LDS per class

typedef float f32x2 __attribute__((ext_vector_type(2)));
typedef float f32x4 __attribute__((ext_vector_type(4)));

// Fixed-offset workspace (CMAX-based so host & device agree without reading C):
//   sums[CMAX*D] f32 | counts[CMAX] i32 | base[CMAX] i32 | cursor[CMAX] i32 |
//   gmean[D] f32 | cmean[CMAX*D] f32 | rowid[N] i32
struct Ptrs {
  float* sums;
  int*   counts;
  int*   base;
  int*   cursor;
  float* gmean;
  float* cmean;
};
__device__ __forceinline__ Ptrs get_ptrs(void* ws) {
  Ptrs p;
  p.sums   = reinterpret_cast<float*>(ws);
  p.counts = reinterpret_cast<int*>(p.sums + (size_t)CMAX * D);
  p.base   = p.counts + CMAX;
  p.cursor = p.base + CMAX;
  p.gmean  = reinterpret_cast<float*>(p.cursor + CMAX);
  p.cmean  = p.gmean + D;
  return p;
}
static constexpr size_t FIXED_BYTES =
    ((size_t)CMAX * D + 3 * (size_t)CMAX + D + (size_t)CMAX * D) * 4;

__device__ __forceinline__ int clampc(int c, int C) {
  return min(max(c, 0), C - 1);
}

// ---------- sort pipeline ----------

__global__ void zero_counts_kernel(void* ws) {
  get_ptrs(ws).counts[threadIdx.x] = 0;  // <<<1, CMAX>>>
}

// S1: per-block LDS histogram of y, merged with global int atomics.
__global__ void count_kernel(const int* __restrict__ y,
                             const int* __restrict__ ncp, void* ws, int n) {
  __shared__ int lh[CMAX];
  const int C = min(*ncp, CMAX);
  Ptrs p = get_ptrs(ws);
  for (int i = threadIdx.x; i < CMAX; i += blockDim.x) lh[i] = 0;
  __syncthreads();
  for (int i = blockIdx.x * blockDim.x + threadIdx.x; i < n;
       i += gridDim.x * blockDim.x)
    atomicAdd(&lh[clampc(y[i], C)], 1);
  __syncthreads();
  for (int c = threadIdx.x; c < CMAX; c += blockDim.x)
    if (lh[c]) atomicAdd(&p.counts[c], lh[c]);
}

// S2: exclusive scan of counts -> base (segment starts) + cursor (working).
__global__ void scan_kernel(void* ws) {  // <<<1, CMAX>>>
  Ptrs p = get_ptrs(ws);
  __shared__ int s[CMAX];
  const int t  = threadIdx.x;
  const int my = p.counts[t];
  s[t] = my;
  __syncthreads();
  for (int off = 1; off < CMAX; off <<= 1) {
    const int add = (t >= off) ? s[t - off] : 0;
    __syncthreads();
    s[t] += add;
    __syncthreads();
  }
  const int excl = s[t] - my;
  p.base[t]   = excl;
  p.cursor[t] = excl;
}

// S3: scatter row ids into class-sorted order. 64 fat blocks -> ~15 consecutive
// slots per class per block (~62B write runs). One batched global reservation
// per present class; no per-row global atomics.
__global__ void scatter_kernel(const int* __restrict__ y,
                               const int* __restrict__ ncp, void* ws,
                               int* __restrict__ rowid, int n, int rpb) {
  __shared__ int lcnt[CMAX];
  __shared__ int lbase[CMAX];
  const int C = min(*ncp, CMAX);
  Ptrs p = get_ptrs(ws);
  for (int i = threadIdx.x; i < CMAX; i += blockDim.x) lcnt[i] = 0;
  __syncthreads();
  const int r0 = blockIdx.x * rpb;
  const int r1 = min(r0 + rpb, n);
  for (int i = r0 + threadIdx.x; i < r1; i += blockDim.x)
    atomicAdd(&lcnt[clampc(y[i], C)], 1);
  __syncthreads();
  for (int c = threadIdx.x; c < CMAX; c += blockDim.x) {
    const int k = lcnt[c];
    lbase[c] = k ? atomicAdd(&p.cursor[c], k) : 0;
    lcnt[c]  = 0;
  }
  __syncthreads();
  for (int i = r0 + threadIdx.x; i < r1; i += blockDim.x) {
    const int c   = clampc(y[i], C);
    const int pos = lbase[c] + atomicAdd(&lcnt[c], 1);
    rowid[pos] = i;
  }
}

// S4: one block per class. Stage rowids in LDS (breaks the rowid->X dependent
// chain), gather full 512B rows (one wave = one row, float2/lane) with 4 rows
// in flight, accumulate in registers, AND write the row to out[:,0:128]
// (scattered 512B-aligned NT stores) so the writer never re-reads X.
__global__ __launch_bounds__(512) void gather_kernel(
    const float* __restrict__ X, const int* __restrict__ ncp, void* ws,
    const int* __restrict__ rowid, float* __restrict__ out) {
  __shared__ int   lrid[RCAP];
  __shared__ f32x2 red[8][D2];
  const int C = min(*ncp, CMAX);
  Ptrs p = get_ptrs(ws);
  const int c   = blockIdx.x;
  const int cnt = (c < C) ? p.counts[c] : 0;
  const int b   = (c < C) ? p.base[c] : 0;
  const int m   = min(cnt, RCAP);
  for (int i = threadIdx.x; i < m; i += blockDim.x) lrid[i] = rowid[b + i];
  __syncthreads();

  const int d2  = threadIdx.x & (D2 - 1);  // float2 slot in row
  const int sub = threadIdx.x >> 6;        // wave id 0..7
  const f32x2* X2 = reinterpret_cast<const f32x2*>(X);
  f32x2*       o2 = reinterpret_cast<f32x2*>(out);
  f32x2 acc = {0.f, 0.f};
  int i = sub;
  for (; i + 24 < m; i += 32) {  // 4 rows in flight per wave
    const int ra = lrid[i], rb = lrid[i + 8], rc = lrid[i + 16], rd = lrid[i + 24];
    const f32x2 va = __builtin_nontemporal_load(&X2[(size_t)ra * D2 + d2]);
    const f32x2 vb = __builtin_nontemporal_load(&X2[(size_t)rb * D2 + d2]);
    const f32x2 vc = __builtin_nontemporal_load(&X2[(size_t)rc * D2 + d2]);
    const f32x2 vd = __builtin_nontemporal_load(&X2[(size_t)rd * D2 + d2]);
    __builtin_nontemporal_store(va, &o2[(size_t)ra * 192 + d2]);
    __builtin_nontemporal_store(vb, &o2[(size_t)rb * 192 + d2]);
    __builtin_nontemporal_store(vc, &o2[(size_t)rc * 192 + d2]);
    __builtin_nontemporal_store(vd, &o2[(size_t)rd * 192 + d2]);
    acc += va + vb + vc + vd;
  }
  for (; i < m; i += 8) {
    const int r = lrid[i];
    const f32x2 v = __builtin_nontemporal_load(&X2[(size_t)r * D2 + d2]);
    __builtin_nontemporal_store(v, &o2[(size_t)r * 192 + d2]);
    acc += v;
  }
  for (int k = RCAP + sub; k < cnt; k += 8) {  // overflow classes (rare)
    const int r = rowid[b + k];
    const f32x2 v = __builtin_nontemporal_load(&X2[(size_t)r * D2 + d2]);
    __builtin_nontemporal_store(v, &o2[(size_t)r * 192 + d2]);
    acc += v;
  }
  red[sub][d2] = acc;
  __syncthreads();
  if (sub == 0) {
    f32x2 t = acc;
#pragma unroll
    for (int k = 1; k < 8; ++k) t += red[k][d2];
    reinterpret_cast<f32x2*>(p.sums)[(size_t)c * D2 + d2] = t;
  }
}

// ---------- fallback accumulate (ws too small): global fp32 atomics ----------

__global__ void zero_sums_counts_kernel(void* ws) {
  int* w = reinterpret_cast<int*>(ws);
  const int total = CMAX * D + CMAX;
  for (int i = blockIdx.x * blockDim.x + threadIdx.x; i < total;
       i += gridDim.x * blockDim.x)
    w[i] = 0;
}

__global__ void accum_atomic_kernel(const float* __restrict__ X,
                                    const int* __restrict__ y,
                                    const int* __restrict__ ncp, void* ws,
                                    int n) {
  const int C = min(*ncp, CMAX);
  Ptrs p = get_ptrs(ws);
  const int g    = threadIdx.x >> 5;
  const int lane = threadIdx.x & 31;
  const long long stride = (long long)gridDim.x * 8;
  for (long long row = (long long)blockIdx.x * 8 + g; row < n; row += stride) {
    const int c = clampc(y[row], C);
    const float4 v = reinterpret_cast<const float4*>(X)[row * D4 + lane];
    float* s = p.sums + (size_t)c * D + lane * 4;
    unsafeAtomicAdd(s + 0, v.x);
    unsafeAtomicAdd(s + 1, v.y);
    unsafeAtomicAdd(s + 2, v.z);
    unsafeAtomicAdd(s + 3, v.w);
    if (lane == 0) atomicAdd(p.counts + c, 1);
  }
}

// ---------- means ----------

__global__ void gmean_kernel(void* ws, const int* __restrict__ ncp, float invN) {
  const int C = min(*ncp, CMAX);
  Ptrs p = get_ptrs(ws);
  __shared__ float red[8][D];
  const int d = threadIdx.x & (D - 1);
  const int g = threadIdx.x >> 7;
  float acc = 0.f;
  for (int c = g; c < C; c += 8) acc += p.sums[c * D + d];
  red[g][d] = acc;
  __syncthreads();
  if (g == 0) {
    float t = 0.f;
#pragma unroll
    for (int k = 0; k < 8; ++k) t += red[k][d];
    p.gmean[d] = t * invN;
  }
}

__global__ void cmean_kernel(void* ws, const int* __restrict__ ncp) {
  const int C = min(*ncp, CMAX);
  Ptrs p = get_ptrs(ws);
  const int total = C * D;
  for (int i = blockIdx.x * blockDim.x + threadIdx.x; i < total;
       i += gridDim.x * blockDim.x) {
    const int cnt = p.counts[i >> 7];
    p.cmean[i] = (cnt > 0) ? (p.sums[i] / (float)cnt) : p.gmean[i & (D - 1)];
  }
}

// ---------- writers ----------

// Sorted path: X third already written by gather. One wave per row writes the
// contiguous 1024B [gmean | cmean[y]] portion: lanes 0-31 gmean (registers),
// lanes 32-63 cmean (L2-resident table).
__global__ __launch_bounds__(256) void write_thirds_kernel(
    const int* __restrict__ y, const int* __restrict__ ncp,
    float* __restrict__ out, void* ws, int n) {
  const int C = min(*ncp, CMAX);
  Ptrs p = get_ptrs(ws);
  const f32x4* gm4 = reinterpret_cast<const f32x4*>(p.gmean);
  const f32x4* cm4 = reinterpret_cast<const f32x4*>(p.cmean);
  f32x4*       o4  = reinterpret_cast<f32x4*>(out);
  const int j  = threadIdx.x & 63;  // slot within [32,96)
  const int lr = threadIdx.x >> 6;  // local row 0..3
  f32x4 vg;
  if (j < D4) vg = gm4[j];  // loop-invariant
  const long long rpi = (long long)gridDim.x * 4;
  for (long long row = (long long)blockIdx.x * 4 + lr; row < n; row += rpi) {
    f32x4 v;
    if (j < D4) {
      v = vg;
    } else {
      const int c = clampc(y[row], C);
      v = cm4[(size_t)c * D4 + (j - D4)];
    }
    __builtin_nontemporal_store(v, &o4[(size_t)row * 96 + D4 + j]);
  }
}

// Fallback path: write full 1536B rows (X re-read sequentially).
__global__ __launch_bounds__(384) void write_full_kernel(
    const float* __restrict__ X, const int* __restrict__ y,
    const int* __restrict__ ncp, float* __restrict__ out, void* ws, int n) {
  const int C = min(*ncp, CMAX);
  Ptrs p = get_ptrs(ws);
  const f32x4* X4  = reinterpret_cast<const f32x4*>(X);
  const f32x4* gm4 = reinterpret_cast<const f32x4*>(p.gmean);
  const f32x4* cm4 = reinterpret_cast<const f32x4*>(p.cmean);
  f32x4*       o4  = reinterpret_cast<f32x4*>(out);
  const int j  = threadIdx.x % 96;
  const int lr = threadIdx.x / 96;
  f32x4 vg;
  if (j >= D4 && j < 2 * D4) vg = gm4[j - D4];
  const long long rpi = (long long)gridDim.x * 4;
  for (long long row = (long long)blockIdx.x * 4 + lr; row < n; row += rpi) {
    f32x4 v;
    if (j < D4) {
      v = __builtin_nontemporal_load(&X4[(size_t)row * D4 + j]);
    } else if (j < 2 * D4) {
      v = vg;
    } else {
      const int c = clampc(y[row], C);
      v = cm4[(size_t)c * D4 + (j - 2 * D4)];
    }
    __builtin_nontemporal_store(v, &o4[(size_t)row * 96 + j]);
  }
}

extern "C" void kernel_launch(void* const* d_in, const int* in_sizes, int n_in,
                              void* d_out, int out_size, void* d_ws,
                              size_t ws_size, hipStream_t stream) {
  const float* X   = reinterpret_cast<const float*>(d_in[0]);
  const int*   y   = reinterpret_cast<const int*>(d_in[1]);
  const int*   ncp = reinterpret_cast<const int*>(d_in[2]);
  float*       out = reinterpret_cast<float*>(d_out);
  const int n = in_sizes[1];  // N = len(y)
  const float invN = 1.0f / (float)n;

  const size_t need = FIXED_BYTES + (size_t)n * sizeof(int);
  if (ws_size >= need) {
    int* rowid = reinterpret_cast<int*>((char*)d_ws + FIXED_BYTES);
    const int rpb = (n + 63) / 64;
    zero_counts_kernel<<<1, CMAX, 0, stream>>>(d_ws);
    count_kernel<<<256, 256, 0, stream>>>(y, ncp, d_ws, n);
    scan_kernel<<<1, CMAX, 0, stream>>>(d_ws);
    scatter_kernel<<<64, 256, 0, stream>>>(y, ncp, d_ws, rowid, n, rpb);
    gather_kernel<<<CMAX, 512, 0, stream>>>(X, ncp, d_ws, rowid, out);
    gmean_kernel<<<1, 1024, 0, stream>>>(d_ws, ncp, invN);
    cmean_kernel<<<512, 256, 0, stream>>>(d_ws, ncp);
    write_thirds_kernel<<<2048, 256, 0, stream>>>(y, ncp, out, d_ws, n);
  } else {
    zero_sums_counts_kernel<<<256, 256, 0, stream>>>(d_ws);
    accum_atomic_kernel<<<4096, 256, 0, stream>>>(X, y, ncp, d_ws, n);
    gmean_kernel<<<1, 1024, 0, stream>>>(d_ws, ncp, invN);
    cmean_kernel<<<512, 256, 0, stream>>>(d_ws, ncp);
    write_full_kernel<<<2048, 384, 0, stream>>>(X, y, ncp, out, d_ws, n);
  }
}

// Round 5
// 471.830 us; speedup vs baseline: 4.5292x; 1.0565x over previous
//
#include <hip/hip_runtime.h>

// out [N, 384] = [X | global_mean | class_mean[y]].  X [N,128] fp32, y [N] i32.
static constexpr int D     = 128;   // feature dim
static constexpr int D4    = 32;    // float4s per row
static constexpr int CMAX  = 1024;  // capacity for classes (C=1000)
static constexpr int SPLIT = 4;     // gather blocks per class
static constexpr int RCAP  = 2048;  // rowids staged in LDS per gather block

typedef float f32x2 __attribute__((ext_vector_type(2)));
typedef float f32x4 __attribute__((ext_vector_type(4)));

// Fixed-offset workspace (CMAX-based so host & device agree without reading C):
//   sums[CMAX*D] | counts[CMAX] | base[CMAX] | cursor[CMAX] | gmean[D] |
//   cmean[CMAX*D] | gpart[8*D] | rowid[N]
struct Ptrs {
  float* sums;
  int*   counts;
  int*   base;
  int*   cursor;
  float* gmean;
  float* cmean;
  float* gpart;
};
__device__ __forceinline__ Ptrs get_ptrs(void* ws) {
  Ptrs p;
  p.sums   = reinterpret_cast<float*>(ws);
  p.counts = reinterpret_cast<int*>(p.sums + (size_t)CMAX * D);
  p.base   = p.counts + CMAX;
  p.cursor = p.base + CMAX;
  p.gmean  = reinterpret_cast<float*>(p.cursor + CMAX);
  p.cmean  = p.gmean + D;
  p.gpart  = p.cmean + (size_t)CMAX * D;
  return p;
}
static constexpr size_t FIXED_BYTES =
    ((size_t)CMAX * D + 3 * (size_t)CMAX + D + (size_t)CMAX * D + 8 * D) * 4;

__device__ __forceinline__ int clampc(int c, int C) {
  return min(max(c, 0), C - 1);
}

// ---------- zero sums + counts ----------
__global__ void zero_kernel(void* ws) {
  int* w = reinterpret_cast<int*>(ws);
  const int total = CMAX * D + CMAX;  // sums + counts
  for (int i = blockIdx.x * blockDim.x + threadIdx.x; i < total;
       i += gridDim.x * blockDim.x)
    w[i] = 0;
}

// ---------- sort pipeline ----------

// S1: per-block LDS histogram of y, merged with global int atomics.
__global__ void count_kernel(const int* __restrict__ y,
                             const int* __restrict__ ncp, void* ws, int n) {
  __shared__ int lh[CMAX];
  const int C = min(*ncp, CMAX);
  Ptrs p = get_ptrs(ws);
  for (int i = threadIdx.x; i < CMAX; i += blockDim.x) lh[i] = 0;
  __syncthreads();
  for (int i = blockIdx.x * blockDim.x + threadIdx.x; i < n;
       i += gridDim.x * blockDim.x)
    atomicAdd(&lh[clampc(y[i], C)], 1);
  __syncthreads();
  for (int c = threadIdx.x; c < CMAX; c += blockDim.x)
    if (lh[c]) atomicAdd(&p.counts[c], lh[c]);
}

// S2: exclusive scan of counts -> base + cursor.
__global__ void scan_kernel(void* ws) {  // <<<1, CMAX>>>
  Ptrs p = get_ptrs(ws);
  __shared__ int s[CMAX];
  const int t  = threadIdx.x;
  const int my = p.counts[t];
  s[t] = my;
  __syncthreads();
  for (int off = 1; off < CMAX; off <<= 1) {
    const int add = (t >= off) ? s[t - off] : 0;
    __syncthreads();
    s[t] += add;
    __syncthreads();
  }
  const int excl = s[t] - my;
  p.base[t]   = excl;
  p.cursor[t] = excl;
}

// S3: scatter row ids into class-sorted order. 64 fat blocks, one batched
// global reservation per present class; no per-row global atomics.
__global__ __launch_bounds__(1024) void scatter_kernel(
    const int* __restrict__ y, const int* __restrict__ ncp, void* ws,
    int* __restrict__ rowid, int n, int rpb) {
  __shared__ int lcnt[CMAX];
  __shared__ int lbase[CMAX];
  const int C = min(*ncp, CMAX);
  Ptrs p = get_ptrs(ws);
  for (int i = threadIdx.x; i < CMAX; i += blockDim.x) lcnt[i] = 0;
  __syncthreads();
  const int r0 = blockIdx.x * rpb;
  const int r1 = min(r0 + rpb, n);
  for (int i = r0 + threadIdx.x; i < r1; i += blockDim.x)
    atomicAdd(&lcnt[clampc(y[i], C)], 1);
  __syncthreads();
  for (int c = threadIdx.x; c < CMAX; c += blockDim.x) {
    const int k = lcnt[c];
    lbase[c] = k ? atomicAdd(&p.cursor[c], k) : 0;
    lcnt[c]  = 0;
  }
  __syncthreads();
  for (int i = r0 + threadIdx.x; i < r1; i += blockDim.x) {
    const int c   = clampc(y[i], C);
    const int pos = lbase[c] + atomicAdd(&lcnt[c], 1);
    rowid[pos] = i;
  }
}

// S4: gather. grid = SPLIT*CMAX; block (c, s) handles slice s of class c's
// rowids. One wave = 2 rows in flight (lane-half = row, f32x4/lane), 4-pair
// unroll -> 8 outstanding 512B rows/wave. Copies each row to out[:,0:128]
// (NT) and register-accumulates; block partial merged into sums via
// unsafeAtomicAdd (sums pre-zeroed).
__global__ __launch_bounds__(512) void gather_kernel(
    const float* __restrict__ X, const int* __restrict__ ncp, void* ws,
    const int* __restrict__ rowid, float* __restrict__ out) {
  __shared__ int   lrid[RCAP];
  __shared__ f32x4 red[16][32];
  const int C = min(*ncp, CMAX);
  Ptrs p = get_ptrs(ws);
  const int c = blockIdx.x & (CMAX - 1);
  const int s = blockIdx.x >> 10;  // split 0..3
  const int cnt = (c < C) ? p.counts[c] : 0;
  if (cnt == 0) return;  // block-uniform
  const int q  = (cnt + SPLIT - 1) / SPLIT;
  const int i0 = s * q;
  if (i0 >= cnt) return;  // block-uniform
  const int i1 = min(i0 + q, cnt);
  const int b  = p.base[c];
  const int m  = i1 - i0;
  const int sm = min(m, RCAP);
  for (int k = threadIdx.x; k < sm; k += blockDim.x) lrid[k] = rowid[b + i0 + k];
  __syncthreads();

  const int lane = threadIdx.x & 63;
  const int d4   = lane & 31;            // float4 slot within row
  const int half = lane >> 5;            // which row of the wave's pair
  const int sub  = threadIdx.x >> 6;     // wave 0..7
  const int slot = sub * 2 + half;       // 0..15
  const f32x4* X4 = reinterpret_cast<const f32x4*>(X);
  f32x4*       o4 = reinterpret_cast<f32x4*>(out);
  f32x4 acc = {0.f, 0.f, 0.f, 0.f};
  int lk = slot;
  for (; lk + 48 < sm; lk += 64) {  // 4 rows in flight per lane-half
    const int ra = lrid[lk], rb = lrid[lk + 16], rc = lrid[lk + 32],
              rd = lrid[lk + 48];
    const f32x4 va = __builtin_nontemporal_load(&X4[(size_t)ra * D4 + d4]);
    const f32x4 vb = __builtin_nontemporal_load(&X4[(size_t)rb * D4 + d4]);
    const f32x4 vc = __builtin_nontemporal_load(&X4[(size_t)rc * D4 + d4]);
    const f32x4 vd = __builtin_nontemporal_load(&X4[(size_t)rd * D4 + d4]);
    __builtin_nontemporal_store(va, &o4[(size_t)ra * 96 + d4]);
    __builtin_nontemporal_store(vb, &o4[(size_t)rb * 96 + d4]);
    __builtin_nontemporal_store(vc, &o4[(size_t)rc * 96 + d4]);
    __builtin_nontemporal_store(vd, &o4[(size_t)rd * 96 + d4]);
    acc += va + vb + vc + vd;
  }
  for (; lk < sm; lk += 16) {
    const int r = lrid[lk];
    const f32x4 v = __builtin_nontemporal_load(&X4[(size_t)r * D4 + d4]);
    __builtin_nontemporal_store(v, &o4[(size_t)r * 96 + d4]);
    acc += v;
  }
  for (int k = i0 + RCAP + slot; k < i1; k += 16) {  // overflow (rare)
    const int r = rowid[b + k];
    const f32x4 v = __builtin_nontemporal_load(&X4[(size_t)r * D4 + d4]);
    __builtin_nontemporal_store(v, &o4[(size_t)r * 96 + d4]);
    acc += v;
  }
  red[slot][d4] = acc;
  __syncthreads();
  if (threadIdx.x < 32) {
    f32x4 t = red[0][threadIdx.x];
#pragma unroll
    for (int k = 1; k < 16; ++k) t += red[k][threadIdx.x];
    float* dst = p.sums + (size_t)c * D + threadIdx.x * 4;
    unsafeAtomicAdd(dst + 0, t.x);
    unsafeAtomicAdd(dst + 1, t.y);
    unsafeAtomicAdd(dst + 2, t.z);
    unsafeAtomicAdd(dst + 3, t.w);
  }
}

// ---------- fallback accumulate (ws too small): global fp32 atomics ----------

__global__ void accum_atomic_kernel(const float* __restrict__ X,
                                    const int* __restrict__ y,
                                    const int* __restrict__ ncp, void* ws,
                                    int n) {
  const int C = min(*ncp, CMAX);
  Ptrs p = get_ptrs(ws);
  const int g    = threadIdx.x >> 5;
  const int lane = threadIdx.x & 31;
  const long long stride = (long long)gridDim.x * 8;
  for (long long row = (long long)blockIdx.x * 8 + g; row < n; row += stride) {
    const int c = clampc(y[row], C);
    const float4 v = reinterpret_cast<const float4*>(X)[row * D4 + lane];
    float* sp = p.sums + (size_t)c * D + lane * 4;
    unsafeAtomicAdd(sp + 0, v.x);
    unsafeAtomicAdd(sp + 1, v.y);
    unsafeAtomicAdd(sp + 2, v.z);
    unsafeAtomicAdd(sp + 3, v.w);
    if (lane == 0) atomicAdd(p.counts + c, 1);
  }
}

// ---------- means ----------

// gmean partial: 8 blocks x 128 dims; block g sums classes [g*128,(g+1)*128).
__global__ void gpart_kernel(void* ws) {  // <<<8, 128>>>
  Ptrs p = get_ptrs(ws);
  const int d = threadIdx.x;
  const int g = blockIdx.x;
  float t = 0.f;
  for (int c = g * 128; c < (g + 1) * 128; ++c) t += p.sums[(size_t)c * D + d];
  p.gpart[g * D + d] = t;
}

__global__ void gmean_final_kernel(void* ws, float invN) {  // <<<1, 128>>>
  Ptrs p = get_ptrs(ws);
  const int d = threadIdx.x;
  float t = 0.f;
#pragma unroll
  for (int g = 0; g < 8; ++g) t += p.gpart[g * D + d];
  p.gmean[d] = t * invN;
}

__global__ void cmean_kernel(void* ws, const int* __restrict__ ncp) {
  const int C = min(*ncp, CMAX);
  Ptrs p = get_ptrs(ws);
  const int total = C * D;
  for (int i = blockIdx.x * blockDim.x + threadIdx.x; i < total;
       i += gridDim.x * blockDim.x) {
    const int cnt = p.counts[i >> 7];
    p.cmean[i] = (cnt > 0) ? (p.sums[i] / (float)cnt) : p.gmean[i & (D - 1)];
  }
}

// ---------- writers ----------

// Sorted path: X third already written by gather. One wave per row writes the
// contiguous 1024B [gmean | cmean[y]] portion: lanes 0-31 gmean (registers),
// lanes 32-63 cmean (L2-resident table).
__global__ __launch_bounds__(512) void write_thirds_kernel(
    const int* __restrict__ y, const int* __restrict__ ncp,
    float* __restrict__ out, void* ws, int n) {
  const int C = min(*ncp, CMAX);
  Ptrs p = get_ptrs(ws);
  const f32x4* gm4 = reinterpret_cast<const f32x4*>(p.gmean);
  const f32x4* cm4 = reinterpret_cast<const f32x4*>(p.cmean);
  f32x4*       o4  = reinterpret_cast<f32x4*>(out);
  const int j  = threadIdx.x & 63;  // slot within [32,96)
  const int lr = threadIdx.x >> 6;  // local row 0..7
  f32x4 vg;
  if (j < D4) vg = gm4[j];  // loop-invariant
  const long long rpi = (long long)gridDim.x * 8;
  for (long long row = (long long)blockIdx.x * 8 + lr; row < n; row += rpi) {
    f32x4 v;
    if (j < D4) {
      v = vg;
    } else {
      const int c = clampc(y[row], C);
      v = cm4[(size_t)c * D4 + (j - D4)];
    }
    __builtin_nontemporal_store(v, &o4[(size_t)row * 96 + D4 + j]);
  }
}

// Fallback path: write full 1536B rows (X re-read sequentially).
__global__ __launch_bounds__(384) void write_full_kernel(
    const float* __restrict__ X, const int* __restrict__ y,
    const int* __restrict__ ncp, float* __restrict__ out, void* ws, int n) {
  const int C = min(*ncp, CMAX);
  Ptrs p = get_ptrs(ws);
  const f32x4* X4  = reinterpret_cast<const f32x4*>(X);
  const f32x4* gm4 = reinterpret_cast<const f32x4*>(p.gmean);
  const f32x4* cm4 = reinterpret_cast<const f32x4*>(p.cmean);
  f32x4*       o4  = reinterpret_cast<f32x4*>(out);
  const int j  = threadIdx.x % 96;
  const int lr = threadIdx.x / 96;
  f32x4 vg;
  if (j >= D4 && j < 2 * D4) vg = gm4[j - D4];
  const long long rpi = (long long)gridDim.x * 4;
  for (long long row = (long long)blockIdx.x * 4 + lr; row < n; row += rpi) {
    f32x4 v;
    if (j < D4) {
      v = __builtin_nontemporal_load(&X4[(size_t)row * D4 + j]);
    } else if (j < 2 * D4) {
      v = vg;
    } else {
      const int c = clampc(y[row], C);
      v = cm4[(size_t)c * D4 + (j - 2 * D4)];
    }
    __builtin_nontemporal_store(v, &o4[(size_t)row * 96 + j]);
  }
}

extern "C" void kernel_launch(void* const* d_in, const int* in_sizes, int n_in,
                              void* d_out, int out_size, void* d_ws,
                              size_t ws_size, hipStream_t stream) {
  const float* X   = reinterpret_cast<const float*>(d_in[0]);
  const int*   y   = reinterpret_cast<const int*>(d_in[1]);
  const int*   ncp = reinterpret_cast<const int*>(d_in[2]);
  float*       out = reinterpret_cast<float*>(d_out);
  const int n = in_sizes[1];  // N = len(y)
  const float invN = 1.0f / (float)n;

  const size_t need = FIXED_BYTES + (size_t)n * sizeof(int);
  if (ws_size >= need) {
    int* rowid = reinterpret_cast<int*>((char*)d_ws + FIXED_BYTES);
    const int rpb = (n + 63) / 64;
    zero_kernel<<<128, 256, 0, stream>>>(d_ws);
    count_kernel<<<256, 256, 0, stream>>>(y, ncp, d_ws, n);
    scan_kernel<<<1, CMAX, 0, stream>>>(d_ws);
    scatter_kernel<<<64, 1024, 0, stream>>>(y, ncp, d_ws, rowid, n, rpb);
    gather_kernel<<<SPLIT * CMAX, 512, 0, stream>>>(X, ncp, d_ws, rowid, out);
    gpart_kernel<<<8, 128, 0, stream>>>(d_ws);
    gmean_final_kernel<<<1, 128, 0, stream>>>(d_ws, invN);
    cmean_kernel<<<512, 256, 0, stream>>>(d_ws, ncp);
    write_thirds_kernel<<<3072, 512, 0, stream>>>(y, ncp, out, d_ws, n);
  } else {
    zero_kernel<<<128, 256, 0, stream>>>(d_ws);
    accum_atomic_kernel<<<4096, 256, 0, stream>>>(X, y, ncp, d_ws, n);
    gpart_kernel<<<8, 128, 0, stream>>>(d_ws);
    gmean_final_kernel<<<1, 128, 0, stream>>>(d_ws, invN);
    cmean_kernel<<<512, 256, 0, stream>>>(d_ws, ncp);
    write_full_kernel<<<2048, 384, 0, stream>>>(X, y, ncp, out, d_ws, n);
  }
}

// Round 6
// 471.123 us; speedup vs baseline: 4.5360x; 1.0015x over previous
//
#include <hip/hip_runtime.h>

// out [N, 384] = [X | global_mean | class_mean[y]].  X [N,128] fp32, y [N] i32.
static constexpr int D     = 128;   // feature dim
static constexpr int D4    = 32;    // float4s per row
static constexpr int CMAX  = 1024;  // capacity for classes (C=1000)
static constexpr int SPLIT = 4;     // gather blocks per class
static constexpr int RCAP  = 2048;  // rowids staged in LDS per gather block

typedef float f32x2 __attribute__((ext_vector_type(2)));
typedef float f32x4 __attribute__((ext_vector_type(4)));

// Fixed-offset workspace (CMAX-based so host & device agree without reading C):
//   sums[CMAX*D] | counts[CMAX] | base[CMAX] | cursor[CMAX] | gmean[D] |
//   cmean[CMAX*D] | gpart[8*D] | rowid[N]
struct Ptrs {
  float* sums;
  int*   counts;
  int*   base;
  int*   cursor;
  float* gmean;
  float* cmean;
  float* gpart;
};
__device__ __forceinline__ Ptrs get_ptrs(void* ws) {
  Ptrs p;
  p.sums   = reinterpret_cast<float*>(ws);
  p.counts = reinterpret_cast<int*>(p.sums + (size_t)CMAX * D);
  p.base   = p.counts + CMAX;
  p.cursor = p.base + CMAX;
  p.gmean  = reinterpret_cast<float*>(p.cursor + CMAX);
  p.cmean  = p.gmean + D;
  p.gpart  = p.cmean + (size_t)CMAX * D;
  return p;
}
static constexpr size_t FIXED_BYTES =
    ((size_t)CMAX * D + 3 * (size_t)CMAX + D + (size_t)CMAX * D + 8 * D) * 4;

__device__ __forceinline__ int clampc(int c, int C) {
  return min(max(c, 0), C - 1);
}

// ---------- zero sums + counts ----------
__global__ void zero_kernel(void* ws) {
  int* w = reinterpret_cast<int*>(ws);
  const int total = CMAX * D + CMAX;  // sums + counts
  for (int i = blockIdx.x * blockDim.x + threadIdx.x; i < total;
       i += gridDim.x * blockDim.x)
    w[i] = 0;
}

// ---------- sort pipeline ----------

// S1: per-block LDS histogram of y, merged with global int atomics.
__global__ void count_kernel(const int* __restrict__ y,
                             const int* __restrict__ ncp, void* ws, int n) {
  __shared__ int lh[CMAX];
  const int C = min(*ncp, CMAX);
  Ptrs p = get_ptrs(ws);
  for (int i = threadIdx.x; i < CMAX; i += blockDim.x) lh[i] = 0;
  __syncthreads();
  for (int i = blockIdx.x * blockDim.x + threadIdx.x; i < n;
       i += gridDim.x * blockDim.x)
    atomicAdd(&lh[clampc(y[i], C)], 1);
  __syncthreads();
  for (int c = threadIdx.x; c < CMAX; c += blockDim.x)
    if (lh[c]) atomicAdd(&p.counts[c], lh[c]);
}

// S2: exclusive scan of counts -> base + cursor.
__global__ void scan_kernel(void* ws) {  // <<<1, CMAX>>>
  Ptrs p = get_ptrs(ws);
  __shared__ int s[CMAX];
  const int t  = threadIdx.x;
  const int my = p.counts[t];
  s[t] = my;
  __syncthreads();
  for (int off = 1; off < CMAX; off <<= 1) {
    const int add = (t >= off) ? s[t - off] : 0;
    __syncthreads();
    s[t] += add;
    __syncthreads();
  }
  const int excl = s[t] - my;
  p.base[t]   = excl;
  p.cursor[t] = excl;
}

// S3: scatter row ids into class-sorted order. 128 fat blocks (~8 consecutive
// slots/class/block); one batched global reservation per present class; no
// per-row global atomics.
__global__ __launch_bounds__(1024) void scatter_kernel(
    const int* __restrict__ y, const int* __restrict__ ncp, void* ws,
    int* __restrict__ rowid, int n, int rpb) {
  __shared__ int lcnt[CMAX];
  __shared__ int lbase[CMAX];
  const int C = min(*ncp, CMAX);
  Ptrs p = get_ptrs(ws);
  for (int i = threadIdx.x; i < CMAX; i += blockDim.x) lcnt[i] = 0;
  __syncthreads();
  const int r0 = blockIdx.x * rpb;
  const int r1 = min(r0 + rpb, n);
  for (int i = r0 + threadIdx.x; i < r1; i += blockDim.x)
    atomicAdd(&lcnt[clampc(y[i], C)], 1);
  __syncthreads();
  for (int c = threadIdx.x; c < CMAX; c += blockDim.x) {
    const int k = lcnt[c];
    lbase[c] = k ? atomicAdd(&p.cursor[c], k) : 0;
    lcnt[c]  = 0;
  }
  __syncthreads();
  for (int i = r0 + threadIdx.x; i < r1; i += blockDim.x) {
    const int c   = clampc(y[i], C);
    const int pos = lbase[c] + atomicAdd(&lcnt[c], 1);
    rowid[pos] = i;
  }
}

// S4: gather. grid = SPLIT*CMAX; block (c, s) handles slice s of class c's
// rowids. One wave = 2 row streams (lane-half = row, f32x4/lane); 8 rows in
// flight per lane-half (statically unrolled arrays -> registers). Copies each
// row to out[:,0:128] (NT) and register-accumulates; block partial merged
// into sums via unsafeAtomicAdd (sums pre-zeroed).
__global__ __launch_bounds__(512) void gather_kernel(
    const float* __restrict__ X, const int* __restrict__ ncp, void* ws,
    const int* __restrict__ rowid, float* __restrict__ out) {
  __shared__ int   lrid[RCAP];
  __shared__ f32x4 red[16][32];
  const int C = min(*ncp, CMAX);
  Ptrs p = get_ptrs(ws);
  const int c = blockIdx.x & (CMAX - 1);
  const int s = blockIdx.x >> 10;  // split 0..3
  const int cnt = (c < C) ? p.counts[c] : 0;
  if (cnt == 0) return;  // block-uniform
  const int q  = (cnt + SPLIT - 1) / SPLIT;
  const int i0 = s * q;
  if (i0 >= cnt) return;  // block-uniform
  const int i1 = min(i0 + q, cnt);
  const int b  = p.base[c];
  const int m  = i1 - i0;
  const int sm = min(m, RCAP);
  for (int k = threadIdx.x; k < sm; k += blockDim.x) lrid[k] = rowid[b + i0 + k];
  __syncthreads();

  const int lane = threadIdx.x & 63;
  const int d4   = lane & 31;            // float4 slot within row
  const int half = lane >> 5;            // which row stream of the wave
  const int sub  = threadIdx.x >> 6;     // wave 0..7
  const int slot = sub * 2 + half;       // 0..15
  const f32x4* X4 = reinterpret_cast<const f32x4*>(X);
  f32x4*       o4 = reinterpret_cast<f32x4*>(out);
  f32x4 acc = {0.f, 0.f, 0.f, 0.f};
  int lk = slot;
  for (; lk + 112 < sm; lk += 128) {  // 8 rows in flight per lane-half
    int   r[8];
    f32x4 v[8];
#pragma unroll
    for (int u = 0; u < 8; ++u) r[u] = lrid[lk + 16 * u];
#pragma unroll
    for (int u = 0; u < 8; ++u)
      v[u] = __builtin_nontemporal_load(&X4[(size_t)r[u] * D4 + d4]);
#pragma unroll
    for (int u = 0; u < 8; ++u)
      __builtin_nontemporal_store(v[u], &o4[(size_t)r[u] * 96 + d4]);
#pragma unroll
    for (int u = 0; u < 8; ++u) acc += v[u];
  }
  for (; lk < sm; lk += 16) {
    const int r = lrid[lk];
    const f32x4 v = __builtin_nontemporal_load(&X4[(size_t)r * D4 + d4]);
    __builtin_nontemporal_store(v, &o4[(size_t)r * 96 + d4]);
    acc += v;
  }
  for (int k = i0 + RCAP + slot; k < i1; k += 16) {  // overflow (rare)
    const int r = rowid[b + k];
    const f32x4 v = __builtin_nontemporal_load(&X4[(size_t)r * D4 + d4]);
    __builtin_nontemporal_store(v, &o4[(size_t)r * 96 + d4]);
    acc += v;
  }
  red[slot][d4] = acc;
  __syncthreads();
  if (threadIdx.x < 32) {
    f32x4 t = red[0][threadIdx.x];
#pragma unroll
    for (int k = 1; k < 16; ++k) t += red[k][threadIdx.x];
    float* dst = p.sums + (size_t)c * D + threadIdx.x * 4;
    unsafeAtomicAdd(dst + 0, t.x);
    unsafeAtomicAdd(dst + 1, t.y);
    unsafeAtomicAdd(dst + 2, t.z);
    unsafeAtomicAdd(dst + 3, t.w);
  }
}

// ---------- fallback accumulate (ws too small): global fp32 atomics ----------

__global__ void accum_atomic_kernel(const float* __restrict__ X,
                                    const int* __restrict__ y,
                                    const int* __restrict__ ncp, void* ws,
                                    int n) {
  const int C = min(*ncp, CMAX);
  Ptrs p = get_ptrs(ws);
  const int g    = threadIdx.x >> 5;
  const int lane = threadIdx.x & 31;
  const long long stride = (long long)gridDim.x * 8;
  for (long long row = (long long)blockIdx.x * 8 + g; row < n; row += stride) {
    const int c = clampc(y[row], C);
    const float4 v = reinterpret_cast<const float4*>(X)[row * D4 + lane];
    float* sp = p.sums + (size_t)c * D + lane * 4;
    unsafeAtomicAdd(sp + 0, v.x);
    unsafeAtomicAdd(sp + 1, v.y);
    unsafeAtomicAdd(sp + 2, v.z);
    unsafeAtomicAdd(sp + 3, v.w);
    if (lane == 0) atomicAdd(p.counts + c, 1);
  }
}

// ---------- means ----------

// gmean partial: 8 blocks x 128 dims; block g sums classes [g*128,(g+1)*128).
__global__ void gpart_kernel(void* ws) {  // <<<8, 128>>>
  Ptrs p = get_ptrs(ws);
  const int d = threadIdx.x;
  const int g = blockIdx.x;
  float t = 0.f;
  for (int c = g * 128; c < (g + 1) * 128; ++c) t += p.sums[(size_t)c * D + d];
  p.gpart[g * D + d] = t;
}

__global__ void gmean_final_kernel(void* ws, float invN) {  // <<<1, 128>>>
  Ptrs p = get_ptrs(ws);
  const int d = threadIdx.x;
  float t = 0.f;
#pragma unroll
  for (int g = 0; g < 8; ++g) t += p.gpart[g * D + d];
  p.gmean[d] = t * invN;
}

__global__ void cmean_kernel(void* ws, const int* __restrict__ ncp) {
  const int C = min(*ncp, CMAX);
  Ptrs p = get_ptrs(ws);
  const int total = C * D;
  for (int i = blockIdx.x * blockDim.x + threadIdx.x; i < total;
       i += gridDim.x * blockDim.x) {
    const int cnt = p.counts[i >> 7];
    p.cmean[i] = (cnt > 0) ? (p.sums[i] / (float)cnt) : p.gmean[i & (D - 1)];
  }
}

// ---------- writers ----------

// Sorted path: X third already written by gather. One wave per row writes the
// contiguous 1024B [gmean | cmean[y]] portion: lanes 0-31 gmean (registers),
// lanes 32-63 cmean (L2-resident table).
__global__ __launch_bounds__(512) void write_thirds_kernel(
    const int* __restrict__ y, const int* __restrict__ ncp,
    float* __restrict__ out, void* ws, int n) {
  const int C = min(*ncp, CMAX);
  Ptrs p = get_ptrs(ws);
  const f32x4* gm4 = reinterpret_cast<const f32x4*>(p.gmean);
  const f32x4* cm4 = reinterpret_cast<const f32x4*>(p.cmean);
  f32x4*       o4  = reinterpret_cast<f32x4*>(out);
  const int j  = threadIdx.x & 63;  // slot within [32,96)
  const int lr = threadIdx.x >> 6;  // local row 0..7
  f32x4 vg;
  if (j < D4) vg = gm4[j];  // loop-invariant
  const long long rpi = (long long)gridDim.x * 8;
  for (long long row = (long long)blockIdx.x * 8 + lr; row < n; row += rpi) {
    f32x4 v;
    if (j < D4) {
      v = vg;
    } else {
      const int c = clampc(y[row], C);
      v = cm4[(size_t)c * D4 + (j - D4)];
    }
    __builtin_nontemporal_store(v, &o4[(size_t)row * 96 + D4 + j]);
  }
}

// Fallback path: write full 1536B rows (X re-read sequentially).
__global__ __launch_bounds__(384) void write_full_kernel(
    const float* __restrict__ X, const int* __restrict__ y,
    const int* __restrict__ ncp, float* __restrict__ out, void* ws, int n) {
  const int C = min(*ncp, CMAX);
  Ptrs p = get_ptrs(ws);
  const f32x4* X4  = reinterpret_cast<const f32x4*>(X);
  const f32x4* gm4 = reinterpret_cast<const f32x4*>(p.gmean);
  const f32x4* cm4 = reinterpret_cast<const f32x4*>(p.cmean);
  f32x4*       o4  = reinterpret_cast<f32x4*>(out);
  const int j  = threadIdx.x % 96;
  const int lr = threadIdx.x / 96;
  f32x4 vg;
  if (j >= D4 && j < 2 * D4) vg = gm4[j - D4];
  const long long rpi = (long long)gridDim.x * 4;
  for (long long row = (long long)blockIdx.x * 4 + lr; row < n; row += rpi) {
    f32x4 v;
    if (j < D4) {
      v = __builtin_nontemporal_load(&X4[(size_t)row * D4 + j]);
    } else if (j < 2 * D4) {
      v = vg;
    } else {
      const int c = clampc(y[row], C);
      v = cm4[(size_t)c * D4 + (j - 2 * D4)];
    }
    __builtin_nontemporal_store(v, &o4[(size_t)row * 96 + j]);
  }
}

extern "C" void kernel_launch(void* const* d_in, const int* in_sizes, int n_in,
                              void* d_out, int out_size, void* d_ws,
                              size_t ws_size, hipStream_t stream) {
  const float* X   = reinterpret_cast<const float*>(d_in[0]);
  const int*   y   = reinterpret_cast<const int*>(d_in[1]);
  const int*   ncp = reinterpret_cast<const int*>(d_in[2]);
  float*       out = reinterpret_cast<float*>(d_out);
  const int n = in_sizes[1];  // N = len(y)
  const float invN = 1.0f / (float)n;

  const size_t need = FIXED_BYTES + (size_t)n * sizeof(int);
  if (ws_size >= need) {
    int* rowid = reinterpret_cast<int*>((char*)d_ws + FIXED_BYTES);
    const int rpb = (n + 127) / 128;
    zero_kernel<<<128, 256, 0, stream>>>(d_ws);
    count_kernel<<<256, 256, 0, stream>>>(y, ncp, d_ws, n);
    scan_kernel<<<1, CMAX, 0, stream>>>(d_ws);
    scatter_kernel<<<128, 1024, 0, stream>>>(y, ncp, d_ws, rowid, n, rpb);
    gather_kernel<<<SPLIT * CMAX, 512, 0, stream>>>(X, ncp, d_ws, rowid, out);
    gpart_kernel<<<8, 128, 0, stream>>>(d_ws);
    gmean_final_kernel<<<1, 128, 0, stream>>>(d_ws, invN);
    cmean_kernel<<<512, 256, 0, stream>>>(d_ws, ncp);
    write_thirds_kernel<<<3072, 512, 0, stream>>>(y, ncp, out, d_ws, n);
  } else {
    zero_kernel<<<128, 256, 0, stream>>>(d_ws);
    accum_atomic_kernel<<<4096, 256, 0, stream>>>(X, y, ncp, d_ws, n);
    gpart_kernel<<<8, 128, 0, stream>>>(d_ws);
    gmean_final_kernel<<<1, 128, 0, stream>>>(d_ws, invN);
    cmean_kernel<<<512, 256, 0, stream>>>(d_ws, ncp);
    write_full_kernel<<<2048, 384, 0, stream>>>(X, y, ncp, out, d_ws, n);
  }
}